// Round 1
// 1244.876 us; speedup vs baseline: 2.3308x; 2.3308x over previous
//
#include <hip/hip_runtime.h>
#include <math.h>

#define N_TOT 32768
#define K_CB 8192
#define D_DIM 256

#define OUT_IDX  (N_TOT * D_DIM)   // 8388608
#define OUT_LOSS (OUT_IDX + N_TOT) // 8421376
#define OUT_PERP (OUT_LOSS + 1)

// ---- workspace layout (bytes) ----
// A image: 256 rowblocks x 16 tiles (0-7 hi, 8-15 lo) x [128 rows][80B] = 41,943,040
// B image:  64 ntiles    x 16 tiles (0-7 hi, 8-15 lo) x [128 codes][80B] = 10,485,760
#define WS_AIMG   0
#define AIMG_SZ   (256u * 16u * 10240u)
#define WS_BIMG   (WS_AIMG + AIMG_SZ)            // 41,943,040
#define BIMG_SZ   (64u * 16u * 10240u)
#define WS_PART   (WS_BIMG + BIMG_SZ)            // 52,428,800 (8 cb x 32768 x float4)
#define PART_SZ   (8u * 32768u * 16u)
#define WS_ESQ    (WS_PART + PART_SZ)            // 56,623,104 (8192 f32)
#define WS_COUNTS (WS_ESQ + 32768u)              // 56,655,872 (8192 f32)
#define WS_LOSS   (WS_COUNTS + 32768u)           // 56,688,640 (1 f32)

typedef short bf16x8 __attribute__((ext_vector_type(8)));
typedef float f32x4  __attribute__((ext_vector_type(4)));

__device__ __forceinline__ unsigned short f2bf(float x) {  // RNE f32 -> bf16
  unsigned int b = __float_as_uint(x);
  b = b + 0x7FFFu + ((b >> 16) & 1u);
  return (unsigned short)(b >> 16);
}
__device__ __forceinline__ float bf2f(unsigned short h) {
  return __uint_as_float(((unsigned int)h) << 16);
}
__device__ __forceinline__ void gld16(const void* g, void* l) {
  __builtin_amdgcn_global_load_lds(
      (const __attribute__((address_space(1))) void*)g,
      (__attribute__((address_space(3))) void*)l, 16, 0, 0);
}

// ---------------- prep: Z -> bf16 hi/lo tile image ----------------
__global__ __launch_bounds__(256) void prep_z(const float* __restrict__ Z,
                                              char* __restrict__ Aimg) {
  const int row = blockIdx.x * 4 + (threadIdx.x >> 6);
  const int lane = threadIdx.x & 63;
  const int rb = row >> 7, r = row & 127;
  const float4 z = *(const float4*)(Z + (size_t)row * D_DIM + lane * 4);
  ushort4 h, l; float t;
  h.x = f2bf(z.x); t = z.x - bf2f(h.x); l.x = f2bf(t);
  h.y = f2bf(z.y); t = z.y - bf2f(h.y); l.y = f2bf(t);
  h.z = f2bf(z.z); t = z.z - bf2f(h.z); l.z = f2bf(t);
  h.w = f2bf(z.w); t = z.w - bf2f(h.w); l.w = f2bf(t);
  const int kt = lane >> 3;                 // 0..7 (32 dims per tile)
  const int off = r * 80 + (lane & 7) * 8;  // 80B padded rows (bank spread)
  *(ushort4*)(Aimg + (size_t)(rb * 16 + kt) * 10240 + off) = h;
  *(ushort4*)(Aimg + (size_t)(rb * 16 + 8 + kt) * 10240 + off) = l;
}

// ---------------- prep: E -> bf16 hi/lo tile image + e_sq ----------------
__global__ __launch_bounds__(256) void prep_e(const float* __restrict__ E,
                                              char* __restrict__ Bimg,
                                              float* __restrict__ esqg) {
  const int code = blockIdx.x * 4 + (threadIdx.x >> 6);
  const int lane = threadIdx.x & 63;
  const int ntg = code >> 7, c = code & 127;
  const float4 e = *(const float4*)(E + (size_t)code * D_DIM + lane * 4);
  ushort4 h, l; float t;
  h.x = f2bf(e.x); t = e.x - bf2f(h.x); l.x = f2bf(t);
  h.y = f2bf(e.y); t = e.y - bf2f(h.y); l.y = f2bf(t);
  h.z = f2bf(e.z); t = e.z - bf2f(h.z); l.z = f2bf(t);
  h.w = f2bf(e.w); t = e.w - bf2f(h.w); l.w = f2bf(t);
  const int kt = lane >> 3;
  const int off = c * 80 + (lane & 7) * 8;
  *(ushort4*)(Bimg + (size_t)(ntg * 16 + kt) * 10240 + off) = h;
  *(ushort4*)(Bimg + (size_t)(ntg * 16 + 8 + kt) * 10240 + off) = l;
  float s = e.x * e.x + e.y * e.y + e.z * e.z + e.w * e.w;
#pragma unroll
  for (int o = 32; o > 0; o >>= 1) s += __shfl_down(s, o);
  if (lane == 0) esqg[code] = s;
}

// ---------------- MFMA distance GEMM + fused top-2 argmin ----------------
// K' = 768: kt 0-7 = z_hi*e_hi, kt 8-15 = z_hi*e_lo, kt 16-23 = z_lo*e_hi.
// Block: 256 thr = 4 waves (2x2), tile 128 rows x 128 codes, m97 structure.
// grid 2048: cb = bid&7 (XCD-local B image), rb = bid>>3.
__global__ __launch_bounds__(256, 2) void argmin_mfma(
    const char* __restrict__ Aimg, const char* __restrict__ Bimg,
    const float* __restrict__ esqg, float4* __restrict__ partials) {
  __shared__ union {
    struct { char A[10240]; char B[10240]; } t;                       // 20.5 KB
    struct { float v1[128][33]; int c1[128][33];
             float v2[128][33]; int c2[128][33]; } m;                 // 67.6 KB
  } u;
  __shared__ float esq_s[128];

  const int tid = threadIdx.x;
  const int lane = tid & 63;
  const int wid = tid >> 6;
  const int wrow = wid >> 1, wcol = wid & 1;
  const int lrow = lane & 15, lgrp = lane >> 4;
  const int cb = blockIdx.x & 7;
  const int rb = blockIdx.x >> 3;

  float s1[16], s2[16]; int c1[16], c2[16];
#pragma unroll
  for (int i = 0; i < 16; i++) { s1[i] = 3.4e38f; s2[i] = 3.4e38f; c1[i] = 0; c2[i] = 0; }

  const char* Ab = (const char*)u.t.A + (wrow * 64 + lrow) * 80 + lgrp * 16;
  const char* Bb = (const char*)u.t.B + (wcol * 64 + lrow) * 80 + lgrp * 16;

  for (int nt = 0; nt < 8; nt++) {
    const int ntg = cb * 8 + nt;
    f32x4 acc[4][4];
#pragma unroll
    for (int i = 0; i < 4; i++)
#pragma unroll
      for (int j = 0; j < 4; j++) acc[i][j] = (f32x4){0.f, 0.f, 0.f, 0.f};

    for (int kt = 0; kt < 24; kt++) {
      __syncthreads();  // prior LDS reads done before restage
      const char* asrc = Aimg + (size_t)(rb * 16 + (kt & 7) + ((kt & 16) ? 8 : 0)) * 10240;
      const char* bsrc = Bimg + (size_t)(ntg * 16 + ((kt < 16) ? kt : kt - 16)) * 10240;
      gld16(asrc + tid * 16,         u.t.A + tid * 16);
      gld16(asrc + (tid + 256) * 16, u.t.A + (tid + 256) * 16);
      if (tid < 128) gld16(asrc + (tid + 512) * 16, u.t.A + (tid + 512) * 16);
      gld16(bsrc + tid * 16,         u.t.B + tid * 16);
      gld16(bsrc + (tid + 256) * 16, u.t.B + (tid + 256) * 16);
      if (tid < 128) gld16(bsrc + (tid + 512) * 16, u.t.B + (tid + 512) * 16);
      if (kt == 0 && tid < 128) esq_s[tid] = esqg[ntg * 128 + tid];
      __syncthreads();

      bf16x8 af[4], bf[4];
#pragma unroll
      for (int rf = 0; rf < 4; rf++) af[rf] = *(const bf16x8*)(Ab + rf * (16 * 80));
#pragma unroll
      for (int cf = 0; cf < 4; cf++) bf[cf] = *(const bf16x8*)(Bb + cf * (16 * 80));
#pragma unroll
      for (int rf = 0; rf < 4; rf++)
#pragma unroll
        for (int cf = 0; cf < 4; cf++)
          acc[rf][cf] = __builtin_amdgcn_mfma_f32_16x16x32_bf16(af[rf], bf[cf], acc[rf][cf], 0, 0, 0);
    }

    // epilogue: dist = e_sq - 2*dot; funnel max-of-4 -> running per-lane top-2
    float eq[4];
#pragma unroll
    for (int cf = 0; cf < 4; cf++) eq[cf] = esq_s[wcol * 64 + cf * 16 + lrow];
    const int code0 = ntg * 128 + wcol * 64 + lrow;
#pragma unroll
    for (int rf = 0; rf < 4; rf++)
#pragma unroll
      for (int reg = 0; reg < 4; reg++) {
        const int r = rf * 4 + reg;
        float v0 = fmaf(-2.f, acc[rf][0][reg], eq[0]);
        float v1 = fmaf(-2.f, acc[rf][1][reg], eq[1]);
        float v2 = fmaf(-2.f, acc[rf][2][reg], eq[2]);
        float v3 = fmaf(-2.f, acc[rf][3][reg], eq[3]);
        float m01 = fminf(v0, v1); int k01 = (v1 < v0) ? code0 + 16 : code0;
        float m23 = fminf(v2, v3); int k23 = (v3 < v2) ? code0 + 48 : code0 + 32;
        float mm = fminf(m01, m23); int kk = (m23 < m01) ? k23 : k01;
        bool g1 = mm < s1[r];
        bool g2 = mm < s2[r];
        s2[r] = g1 ? s1[r] : (g2 ? mm : s2[r]);
        c2[r] = g1 ? c1[r] : (g2 ? kk : c2[r]);
        s1[r] = g1 ? mm : s1[r];
        c1[r] = g1 ? kk : c1[r];
      }
  }

  __syncthreads();  // all tile reads done; reuse union for merge
#pragma unroll
  for (int rf = 0; rf < 4; rf++)
#pragma unroll
    for (int reg = 0; reg < 4; reg++) {
      const int r = rf * 4 + reg;
      const int row = wrow * 64 + rf * 16 + lgrp * 4 + reg;
      const int slot = wcol * 16 + lrow;
      u.m.v1[row][slot] = s1[r]; u.m.c1[row][slot] = c1[r];
      u.m.v2[row][slot] = s2[r]; u.m.c2[row][slot] = c2[r];
    }
  __syncthreads();
  if (tid < 128) {
    float D1 = 3.4e38f, D2 = 3.4e38f; int C1 = 0, C2 = 0;
    for (int s = 0; s < 32; s++) {
      float a = u.m.v1[tid][s]; int ka = u.m.c1[tid][s];
      float b = u.m.v2[tid][s]; int kb = u.m.c2[tid][s];
      if (a < D1 || (a == D1 && ka < C1)) { D2 = D1; C2 = C1; D1 = a; C1 = ka; }
      else if (a < D2 || (a == D2 && ka < C2)) { D2 = a; C2 = ka; }
      if (b < D1 || (b == D1 && kb < C1)) { D2 = D1; C2 = C1; D1 = b; C1 = kb; }
      else if (b < D2 || (b == D2 && kb < C2)) { D2 = b; C2 = kb; }
    }
    float4 p;
    p.x = D1; p.y = __int_as_float(C1); p.z = D2; p.w = __int_as_float(C2);
    partials[(size_t)cb * N_TOT + rb * 128 + tid] = p;
  }
}

// ---------------- merge codeblock partials + fp64 rescore ----------------
__global__ __launch_bounds__(256) void merge_rescore(
    const float* __restrict__ Z, const float* __restrict__ E,
    const float4* __restrict__ partials, float* __restrict__ out_idx_f) {
  const int row = blockIdx.x * 256 + threadIdx.x;
  float D1 = 3.4e38f, D2 = 3.4e38f; int C1 = 0, C2 = 0;
  for (int cbi = 0; cbi < 8; cbi++) {
    float4 p = partials[(size_t)cbi * N_TOT + row];
    float a = p.x; int ka = __float_as_int(p.y);
    float b = p.z; int kb = __float_as_int(p.w);
    if (a < D1 || (a == D1 && ka < C1)) { D2 = D1; C2 = C1; D1 = a; C1 = ka; }
    else if (a < D2 || (a == D2 && ka < C2)) { D2 = a; C2 = ka; }
    if (b < D1 || (b == D1 && kb < C1)) { D2 = D1; C2 = C1; D1 = b; C1 = kb; }
    else if (b < D2 || (b == D2 && kb < C2)) { D2 = b; C2 = kb; }
  }
  // fp64 rescore of top-2: resolves near-ties against the true distance
  const float* zp = Z + (size_t)row * D_DIM;
  const float* ep1 = E + (size_t)C1 * D_DIM;
  const float* ep2 = E + (size_t)C2 * D_DIM;
  double dd1 = 0.0, dd2 = 0.0;
  for (int d = 0; d < D_DIM; d += 4) {
    const float4 zv = *(const float4*)(zp + d);
    const float4 e1v = *(const float4*)(ep1 + d);
    const float4 e2v = *(const float4*)(ep2 + d);
    double t;
    t = (double)zv.x - (double)e1v.x; dd1 += t * t;
    t = (double)zv.y - (double)e1v.y; dd1 += t * t;
    t = (double)zv.z - (double)e1v.z; dd1 += t * t;
    t = (double)zv.w - (double)e1v.w; dd1 += t * t;
    t = (double)zv.x - (double)e2v.x; dd2 += t * t;
    t = (double)zv.y - (double)e2v.y; dd2 += t * t;
    t = (double)zv.z - (double)e2v.z; dd2 += t * t;
    t = (double)zv.w - (double)e2v.w; dd2 += t * t;
  }
  int fin = C1;
  if (dd2 < dd1 || (dd2 == dd1 && C2 < C1)) fin = C2;
  out_idx_f[row] = (float)fin;
}

// ---------------- gather z_q, accumulate loss sum + counts ----------------
__global__ __launch_bounds__(256) void gather_kernel(
    const float* __restrict__ Z, const float* __restrict__ E,
    const float* __restrict__ idx_f, float* __restrict__ zq_out,
    float* __restrict__ counts, float* __restrict__ loss_sum) {
  const int row = blockIdx.x;
  const int t = threadIdx.x;
  const int c = (int)idx_f[row];
  const float e = E[(size_t)c * D_DIM + t];
  const float z = Z[(size_t)row * D_DIM + t];
  zq_out[(size_t)row * D_DIM + t] = e;
  float sq = (z - e) * (z - e);
#pragma unroll
  for (int off = 32; off > 0; off >>= 1) sq += __shfl_down(sq, off);
  __shared__ float wsum[4];
  if ((t & 63) == 0) wsum[t >> 6] = sq;
  __syncthreads();
  if (t == 0) {
    atomicAdd(loss_sum, wsum[0] + wsum[1] + wsum[2] + wsum[3]);
    atomicAdd(&counts[c], 1.0f);
  }
}

// ---------------- loss scale + perplexity ----------------
__global__ __launch_bounds__(256) void final_kernel(
    const float* __restrict__ counts, const float* __restrict__ loss_sum,
    float* __restrict__ out) {
  const int t = threadIdx.x;
  float h = 0.0f;
  for (int k = t; k < K_CB; k += 256) {
    const float p = counts[k] * (1.0f / (float)N_TOT);
    h += p * logf(p + 1e-12f);
  }
#pragma unroll
  for (int off = 32; off > 0; off >>= 1) h += __shfl_down(h, off);
  __shared__ float ws4[4];
  if ((t & 63) == 0) ws4[t >> 6] = h;
  __syncthreads();
  if (t == 0) {
    const float H = ws4[0] + ws4[1] + ws4[2] + ws4[3];
    out[OUT_LOSS] = 1.25f * loss_sum[0] * (1.0f / (float)(N_TOT * D_DIM));
    out[OUT_PERP] = expf(-H);
  }
}

extern "C" void kernel_launch(void* const* d_in, const int* in_sizes, int n_in,
                              void* d_out, int out_size, void* d_ws, size_t ws_size,
                              hipStream_t stream) {
  (void)in_sizes; (void)n_in; (void)out_size; (void)ws_size;
  const float* Z = (const float*)d_in[0];
  const float* E = (const float*)d_in[1];
  float* out = (float*)d_out;
  char* ws = (char*)d_ws;
  char* Aimg = ws + WS_AIMG;
  char* Bimg = ws + WS_BIMG;
  float4* partials = (float4*)(ws + WS_PART);
  float* esqg = (float*)(ws + WS_ESQ);
  float* counts = (float*)(ws + WS_COUNTS);
  float* loss_sum = (float*)(ws + WS_LOSS);

  hipMemsetAsync(ws + WS_COUNTS, 0, 32768 + 4, stream);  // counts + loss_sum
  prep_z<<<dim3(8192), dim3(256), 0, stream>>>(Z, Aimg);
  prep_e<<<dim3(2048), dim3(256), 0, stream>>>(E, Bimg, esqg);
  argmin_mfma<<<dim3(2048), dim3(256), 0, stream>>>(Aimg, Bimg, esqg, partials);
  merge_rescore<<<dim3(128), dim3(256), 0, stream>>>(Z, E, partials, out + OUT_IDX);
  gather_kernel<<<dim3(N_TOT), dim3(256), 0, stream>>>(Z, E, out + OUT_IDX, out, counts, loss_sum);
  final_kernel<<<dim3(1), dim3(256), 0, stream>>>(counts, loss_sum, out);
}

// Round 2
// 932.209 us; speedup vs baseline: 3.1126x; 1.3354x over previous
//
#include <hip/hip_runtime.h>
#include <math.h>

#define N_TOT 32768
#define K_CB 8192
#define D_DIM 256

#define OUT_IDX  (N_TOT * D_DIM)   // 8388608
#define OUT_LOSS (OUT_IDX + N_TOT) // 8421376
#define OUT_PERP (OUT_LOSS + 1)

// ---- workspace layout (bytes) ----
#define WS_AIMG   0
#define AIMG_SZ   (256u * 16u * 10240u)          // 41,943,040
#define WS_BIMG   (WS_AIMG + AIMG_SZ)
#define BIMG_SZ   (64u * 16u * 10240u)           // 10,485,760
#define WS_PART   (WS_BIMG + BIMG_SZ)            // 8 cb x 32768 x float4
#define PART_SZ   (8u * 32768u * 16u)
#define WS_ESQ    (WS_PART + PART_SZ)            // 8192 f32
#define WS_COUNTS (WS_ESQ + 32768u)              // 8192 f32
#define WS_LPART  (WS_COUNTS + 32768u)           // 2048 f32 loss partials

typedef short bf16x8 __attribute__((ext_vector_type(8)));
typedef float f32x4  __attribute__((ext_vector_type(4)));

__device__ __forceinline__ unsigned short f2bf(float x) {  // RNE f32 -> bf16
  unsigned int b = __float_as_uint(x);
  b = b + 0x7FFFu + ((b >> 16) & 1u);
  return (unsigned short)(b >> 16);
}
__device__ __forceinline__ float bf2f(unsigned short h) {
  return __uint_as_float(((unsigned int)h) << 16);
}
__device__ __forceinline__ void gld16(const void* g, void* l) {
  __builtin_amdgcn_global_load_lds(
      (const __attribute__((address_space(1))) void*)g,
      (__attribute__((address_space(3))) void*)l, 16, 0, 0);
}

// ---------------- prep: Z -> bf16 hi/lo tile image ----------------
__global__ __launch_bounds__(256) void prep_z(const float* __restrict__ Z,
                                              char* __restrict__ Aimg) {
  const int row = blockIdx.x * 4 + (threadIdx.x >> 6);
  const int lane = threadIdx.x & 63;
  const int rb = row >> 7, r = row & 127;
  const float4 z = *(const float4*)(Z + (size_t)row * D_DIM + lane * 4);
  ushort4 h, l; float t;
  h.x = f2bf(z.x); t = z.x - bf2f(h.x); l.x = f2bf(t);
  h.y = f2bf(z.y); t = z.y - bf2f(h.y); l.y = f2bf(t);
  h.z = f2bf(z.z); t = z.z - bf2f(h.z); l.z = f2bf(t);
  h.w = f2bf(z.w); t = z.w - bf2f(h.w); l.w = f2bf(t);
  const int kt = lane >> 3;                 // 0..7 (32 dims per tile)
  const int off = r * 80 + (lane & 7) * 8;  // 80B padded rows (bank spread)
  *(ushort4*)(Aimg + (size_t)(rb * 16 + kt) * 10240 + off) = h;
  *(ushort4*)(Aimg + (size_t)(rb * 16 + 8 + kt) * 10240 + off) = l;
}

// ---------------- prep: E -> bf16 hi/lo tile image + e_sq ----------------
__global__ __launch_bounds__(256) void prep_e(const float* __restrict__ E,
                                              char* __restrict__ Bimg,
                                              float* __restrict__ esqg) {
  const int code = blockIdx.x * 4 + (threadIdx.x >> 6);
  const int lane = threadIdx.x & 63;
  const int ntg = code >> 7, c = code & 127;
  const float4 e = *(const float4*)(E + (size_t)code * D_DIM + lane * 4);
  ushort4 h, l; float t;
  h.x = f2bf(e.x); t = e.x - bf2f(h.x); l.x = f2bf(t);
  h.y = f2bf(e.y); t = e.y - bf2f(h.y); l.y = f2bf(t);
  h.z = f2bf(e.z); t = e.z - bf2f(h.z); l.z = f2bf(t);
  h.w = f2bf(e.w); t = e.w - bf2f(h.w); l.w = f2bf(t);
  const int kt = lane >> 3;
  const int off = c * 80 + (lane & 7) * 8;
  *(ushort4*)(Bimg + (size_t)(ntg * 16 + kt) * 10240 + off) = h;
  *(ushort4*)(Bimg + (size_t)(ntg * 16 + 8 + kt) * 10240 + off) = l;
  float s = e.x * e.x + e.y * e.y + e.z * e.z + e.w * e.w;
#pragma unroll
  for (int o = 32; o > 0; o >>= 1) s += __shfl_down(s, o);
  if (lane == 0) esqg[code] = s;
}

// ---------------- MFMA distance GEMM + fused top-2 argmin ----------------
// K' = 768: kt 0-7 = z_hi*e_hi, kt 8-15 = z_hi*e_lo, kt 16-23 = z_lo*e_hi.
// Block: 256 thr = 4 waves (2x2), tile 128 rows x 128 codes.
// Merge via shfl_xor butterflies + 4KB cross-wave buffer (LDS 68KB -> 21KB).
__global__ __launch_bounds__(256, 4) void argmin_mfma(
    const char* __restrict__ Aimg, const char* __restrict__ Bimg,
    const float* __restrict__ esqg, float4* __restrict__ partials) {
  __shared__ __align__(16) union {
    struct { char A[10240]; char B[10240]; } t;   // 20 KB
    float4 mbuf[128][2];                          // 4 KB (post-loop merge)
  } u;
  __shared__ float esq_s[128];

  const int tid = threadIdx.x;
  const int lane = tid & 63;
  const int wid = tid >> 6;
  const int wrow = wid >> 1, wcol = wid & 1;
  const int lrow = lane & 15, lgrp = lane >> 4;
  const int cb = blockIdx.x & 7;
  const int rb = blockIdx.x >> 3;

  float s1[16], s2[16]; int c1[16], c2[16];
#pragma unroll
  for (int i = 0; i < 16; i++) { s1[i] = 3.4e38f; s2[i] = 3.4e38f; c1[i] = 0; c2[i] = 0; }

  const char* Ab = (const char*)u.t.A + (wrow * 64 + lrow) * 80 + lgrp * 16;
  const char* Bb = (const char*)u.t.B + (wcol * 64 + lrow) * 80 + lgrp * 16;

  for (int nt = 0; nt < 8; nt++) {
    const int ntg = cb * 8 + nt;
    f32x4 acc[4][4];
#pragma unroll
    for (int i = 0; i < 4; i++)
#pragma unroll
      for (int j = 0; j < 4; j++) acc[i][j] = (f32x4){0.f, 0.f, 0.f, 0.f};

    for (int kt = 0; kt < 24; kt++) {
      __syncthreads();  // prior LDS reads done before restage
      const char* asrc = Aimg + (size_t)(rb * 16 + (kt & 7) + ((kt & 16) ? 8 : 0)) * 10240;
      const char* bsrc = Bimg + (size_t)(ntg * 16 + ((kt < 16) ? kt : kt - 16)) * 10240;
      gld16(asrc + tid * 16,         u.t.A + tid * 16);
      gld16(asrc + (tid + 256) * 16, u.t.A + (tid + 256) * 16);
      if (tid < 128) gld16(asrc + (tid + 512) * 16, u.t.A + (tid + 512) * 16);
      gld16(bsrc + tid * 16,         u.t.B + tid * 16);
      gld16(bsrc + (tid + 256) * 16, u.t.B + (tid + 256) * 16);
      if (tid < 128) gld16(bsrc + (tid + 512) * 16, u.t.B + (tid + 512) * 16);
      if (kt == 0 && tid < 128) esq_s[tid] = esqg[ntg * 128 + tid];
      __syncthreads();

      bf16x8 af[4], bf[4];
#pragma unroll
      for (int rf = 0; rf < 4; rf++) af[rf] = *(const bf16x8*)(Ab + rf * (16 * 80));
#pragma unroll
      for (int cf = 0; cf < 4; cf++) bf[cf] = *(const bf16x8*)(Bb + cf * (16 * 80));
#pragma unroll
      for (int rf = 0; rf < 4; rf++)
#pragma unroll
        for (int cf = 0; cf < 4; cf++)
          acc[rf][cf] = __builtin_amdgcn_mfma_f32_16x16x32_bf16(af[rf], bf[cf], acc[rf][cf], 0, 0, 0);
    }

    // epilogue: dist = e_sq - 2*dot; funnel min-of-4 -> running per-lane top-2
    float eq[4];
#pragma unroll
    for (int cf = 0; cf < 4; cf++) eq[cf] = esq_s[wcol * 64 + cf * 16 + lrow];
    const int code0 = ntg * 128 + wcol * 64 + lrow;
#pragma unroll
    for (int rf = 0; rf < 4; rf++)
#pragma unroll
      for (int reg = 0; reg < 4; reg++) {
        const int r = rf * 4 + reg;
        float v0 = fmaf(-2.f, acc[rf][0][reg], eq[0]);
        float v1 = fmaf(-2.f, acc[rf][1][reg], eq[1]);
        float v2 = fmaf(-2.f, acc[rf][2][reg], eq[2]);
        float v3 = fmaf(-2.f, acc[rf][3][reg], eq[3]);
        float m01 = fminf(v0, v1); int k01 = (v1 < v0) ? code0 + 16 : code0;
        float m23 = fminf(v2, v3); int k23 = (v3 < v2) ? code0 + 48 : code0 + 32;
        float mm = fminf(m01, m23); int kk = (m23 < m01) ? k23 : k01;
        bool g1 = mm < s1[r];
        bool g2 = mm < s2[r];
        s2[r] = g1 ? s1[r] : (g2 ? mm : s2[r]);
        c2[r] = g1 ? c1[r] : (g2 ? kk : c2[r]);
        s1[r] = g1 ? mm : s1[r];
        c1[r] = g1 ? kk : c1[r];
      }
  }

  // shuffle-butterfly merge across the 16 lrow lanes (codes disjoint per lane;
  // lexicographic (val, idx) compare preserves lowest-index-wins on ties)
#pragma unroll
  for (int r = 0; r < 16; r++) {
#pragma unroll
    for (int m = 1; m <= 8; m <<= 1) {
      float o1 = __shfl_xor(s1[r], m); int k1 = __shfl_xor(c1[r], m);
      float o2 = __shfl_xor(s2[r], m); int k2 = __shfl_xor(c2[r], m);
      bool t1 = (o1 < s1[r]) || (o1 == s1[r] && k1 < c1[r]);
      bool t2 = (o1 < s2[r]) || (o1 == s2[r] && k1 < c2[r]);
      float ns2 = t1 ? s1[r] : (t2 ? o1 : s2[r]);
      int   nc2 = t1 ? c1[r] : (t2 ? k1 : c2[r]);
      s1[r] = t1 ? o1 : s1[r]; c1[r] = t1 ? k1 : c1[r];
      s2[r] = ns2; c2[r] = nc2;
      bool u1 = (o2 < s1[r]) || (o2 == s1[r] && k2 < c1[r]);
      bool u2 = (o2 < s2[r]) || (o2 == s2[r] && k2 < c2[r]);
      ns2 = u1 ? s1[r] : (u2 ? o2 : s2[r]);
      nc2 = u1 ? c1[r] : (u2 ? k2 : c2[r]);
      s1[r] = u1 ? o2 : s1[r]; c1[r] = u1 ? k2 : c1[r];
      s2[r] = ns2; c2[r] = nc2;
    }
  }

  __syncthreads();  // all tile reads done; reuse union as merge buffer
  if (lrow == 0) {
#pragma unroll
    for (int rf = 0; rf < 4; rf++)
#pragma unroll
      for (int reg = 0; reg < 4; reg++) {
        const int r = rf * 4 + reg;
        const int row = wrow * 64 + rf * 16 + lgrp * 4 + reg;
        float4 p;
        p.x = s1[r]; p.y = __int_as_float(c1[r]);
        p.z = s2[r]; p.w = __int_as_float(c2[r]);
        u.mbuf[row][wcol] = p;
      }
  }
  __syncthreads();
  if (tid < 128) {
    float4 pa = u.mbuf[tid][0];
    float4 pb = u.mbuf[tid][1];
    float D1 = pa.x; int C1 = __float_as_int(pa.y);
    float D2 = pa.z; int C2 = __float_as_int(pa.w);
    float a = pb.x; int ka = __float_as_int(pb.y);
    float b = pb.z; int kb = __float_as_int(pb.w);
    if (a < D1 || (a == D1 && ka < C1)) { D2 = D1; C2 = C1; D1 = a; C1 = ka; }
    else if (a < D2 || (a == D2 && ka < C2)) { D2 = a; C2 = ka; }
    if (b < D1 || (b == D1 && kb < C1)) { D2 = D1; C2 = C1; D1 = b; C1 = kb; }
    else if (b < D2 || (b == D2 && kb < C2)) { D2 = b; C2 = kb; }
    float4 p;
    p.x = D1; p.y = __int_as_float(C1); p.z = D2; p.w = __int_as_float(C2);
    partials[(size_t)cb * N_TOT + rb * 128 + tid] = p;
  }
}

// ---------------- merge codeblock partials + fp64 rescore ----------------
__global__ __launch_bounds__(128) void merge_rescore(
    const float* __restrict__ Z, const float* __restrict__ E,
    const float4* __restrict__ partials, float* __restrict__ out_idx_f) {
  const int row = blockIdx.x * 128 + threadIdx.x;
  float D1 = 3.4e38f, D2 = 3.4e38f; int C1 = 0, C2 = 0;
  for (int cbi = 0; cbi < 8; cbi++) {
    float4 p = partials[(size_t)cbi * N_TOT + row];
    float a = p.x; int ka = __float_as_int(p.y);
    float b = p.z; int kb = __float_as_int(p.w);
    if (a < D1 || (a == D1 && ka < C1)) { D2 = D1; C2 = C1; D1 = a; C1 = ka; }
    else if (a < D2 || (a == D2 && ka < C2)) { D2 = a; C2 = ka; }
    if (b < D1 || (b == D1 && kb < C1)) { D2 = D1; C2 = C1; D1 = b; C1 = kb; }
    else if (b < D2 || (b == D2 && kb < C2)) { D2 = b; C2 = kb; }
  }
  // fp64 rescore of top-2: resolves near-ties against the true distance
  const float* zp = Z + (size_t)row * D_DIM;
  const float* ep1 = E + (size_t)C1 * D_DIM;
  const float* ep2 = E + (size_t)C2 * D_DIM;
  double dd1 = 0.0, dd2 = 0.0;
  for (int d = 0; d < D_DIM; d += 4) {
    const float4 zv = *(const float4*)(zp + d);
    const float4 e1v = *(const float4*)(ep1 + d);
    const float4 e2v = *(const float4*)(ep2 + d);
    double t;
    t = (double)zv.x - (double)e1v.x; dd1 += t * t;
    t = (double)zv.y - (double)e1v.y; dd1 += t * t;
    t = (double)zv.z - (double)e1v.z; dd1 += t * t;
    t = (double)zv.w - (double)e1v.w; dd1 += t * t;
    t = (double)zv.x - (double)e2v.x; dd2 += t * t;
    t = (double)zv.y - (double)e2v.y; dd2 += t * t;
    t = (double)zv.z - (double)e2v.z; dd2 += t * t;
    t = (double)zv.w - (double)e2v.w; dd2 += t * t;
  }
  int fin = C1;
  if (dd2 < dd1 || (dd2 == dd1 && C2 < C1)) fin = C2;
  out_idx_f[row] = (float)fin;
}

// ---------------- gather z_q, loss partial per block (no hot atomic) ----------------
__global__ __launch_bounds__(256) void gather_kernel(
    const float* __restrict__ Z, const float* __restrict__ E,
    const float* __restrict__ idx_f, float* __restrict__ zq_out,
    float* __restrict__ counts, float* __restrict__ loss_part) {
  const int t = threadIdx.x;
  float lsum = 0.0f;
  for (int rr = 0; rr < 16; rr++) {
    const int row = blockIdx.x * 16 + rr;
    const int c = (int)idx_f[row];
    const float e = E[(size_t)c * D_DIM + t];
    const float z = Z[(size_t)row * D_DIM + t];
    zq_out[(size_t)row * D_DIM + t] = e;
    const float d = z - e;
    lsum += d * d;
    if (t == 0) atomicAdd(&counts[c], 1.0f);  // 8192 addresses, low contention
  }
#pragma unroll
  for (int off = 32; off > 0; off >>= 1) lsum += __shfl_down(lsum, off);
  __shared__ float wsum[4];
  if ((t & 63) == 0) wsum[t >> 6] = lsum;
  __syncthreads();
  if (t == 0) loss_part[blockIdx.x] = wsum[0] + wsum[1] + wsum[2] + wsum[3];
}

// ---------------- loss scale + perplexity ----------------
__global__ __launch_bounds__(256) void final_kernel(
    const float* __restrict__ counts, const float* __restrict__ loss_part,
    float* __restrict__ out) {
  const int t = threadIdx.x;
  float h = 0.0f, ls = 0.0f;
  for (int k = t; k < K_CB; k += 256) {
    const float p = counts[k] * (1.0f / (float)N_TOT);
    h += p * logf(p + 1e-12f);
  }
  for (int k = t; k < 2048; k += 256) ls += loss_part[k];
#pragma unroll
  for (int off = 32; off > 0; off >>= 1) {
    h += __shfl_down(h, off);
    ls += __shfl_down(ls, off);
  }
  __shared__ float ws4[4], ls4[4];
  if ((t & 63) == 0) { ws4[t >> 6] = h; ls4[t >> 6] = ls; }
  __syncthreads();
  if (t == 0) {
    const float H = ws4[0] + ws4[1] + ws4[2] + ws4[3];
    const float L = ls4[0] + ls4[1] + ls4[2] + ls4[3];
    out[OUT_LOSS] = 1.25f * L * (1.0f / (float)(N_TOT * D_DIM));
    out[OUT_PERP] = expf(-H);
  }
}

extern "C" void kernel_launch(void* const* d_in, const int* in_sizes, int n_in,
                              void* d_out, int out_size, void* d_ws, size_t ws_size,
                              hipStream_t stream) {
  (void)in_sizes; (void)n_in; (void)out_size; (void)ws_size;
  const float* Z = (const float*)d_in[0];
  const float* E = (const float*)d_in[1];
  float* out = (float*)d_out;
  char* ws = (char*)d_ws;
  char* Aimg = ws + WS_AIMG;
  char* Bimg = ws + WS_BIMG;
  float4* partials = (float4*)(ws + WS_PART);
  float* esqg = (float*)(ws + WS_ESQ);
  float* counts = (float*)(ws + WS_COUNTS);
  float* loss_part = (float*)(ws + WS_LPART);

  hipMemsetAsync(ws + WS_COUNTS, 0, 32768, stream);  // counts only
  prep_z<<<dim3(8192), dim3(256), 0, stream>>>(Z, Aimg);
  prep_e<<<dim3(2048), dim3(256), 0, stream>>>(E, Bimg, esqg);
  argmin_mfma<<<dim3(2048), dim3(256), 0, stream>>>(Aimg, Bimg, esqg, partials);
  merge_rescore<<<dim3(256), dim3(128), 0, stream>>>(Z, E, partials, out + OUT_IDX);
  gather_kernel<<<dim3(2048), dim3(256), 0, stream>>>(Z, E, out + OUT_IDX, out, counts, loss_part);
  final_kernel<<<dim3(1), dim3(256), 0, stream>>>(counts, loss_part, out);
}

// Round 4
// 861.897 us; speedup vs baseline: 3.3665x; 1.0816x over previous
//
#include <hip/hip_runtime.h>
#include <math.h>

#define N_TOT 32768
#define K_CB 8192
#define D_DIM 256

#define OUT_IDX  (N_TOT * D_DIM)   // 8388608
#define OUT_LOSS (OUT_IDX + N_TOT) // 8421376
#define OUT_PERP (OUT_LOSS + 1)

// ---- workspace layout (bytes), total 50,405,376 (< proven 56.7 MB) ----
// A image: 256 rb x 16 tiles (0-7 hi, 8-15 lo) x [128 rows][64B packed, chunk-swizzled]
// B image:  64 ntg x 16 tiles x [128 codes][64B]
#define WS_AIMG   0u
#define AIMG_SZ   (256u * 16u * 8192u)           // 33,554,432
#define WS_BIMG   (WS_AIMG + AIMG_SZ)
#define BIMG_SZ   (64u * 16u * 8192u)            // 8,388,608
#define WS_PART   (WS_BIMG + BIMG_SZ)            // 16 slices x 32768 x float4
#define PART_SZ   (16u * 32768u * 16u)           // 8,388,608
#define WS_ESQ    (WS_PART + PART_SZ)            // 8192 f32
#define WS_COUNTS (WS_ESQ + 32768u)              // 8192 f32
#define WS_LPART  (WS_COUNTS + 32768u)           // 2048 f32 loss partials

typedef short bf16x8 __attribute__((ext_vector_type(8)));
typedef float f32x4  __attribute__((ext_vector_type(4)));
typedef unsigned short u16x8 __attribute__((ext_vector_type(8)));

__device__ __forceinline__ unsigned short f2bf(float x) {  // RNE f32 -> bf16
  unsigned int b = __float_as_uint(x);
  b = b + 0x7FFFu + ((b >> 16) & 1u);
  return (unsigned short)(b >> 16);
}
__device__ __forceinline__ float bf2f(unsigned short h) {
  return __uint_as_float(((unsigned int)h) << 16);
}
__device__ __forceinline__ void gld16(const void* g, void* l) {
  __builtin_amdgcn_global_load_lds(
      (const __attribute__((address_space(1))) void*)g,
      (__attribute__((address_space(3))) void*)l, 16, 0, 0);
}

// ---------------- prep: Z -> packed swizzled bf16 hi/lo tile image ----------------
// Chunk c of row r stored at slot c ^ ((r>>1)&3): linear global_load_lds lands it
// pre-swizzled; the frag ds_read applies the same XOR (both-sides rule).
__global__ __launch_bounds__(256) void prep_z(const float* __restrict__ Z,
                                              char* __restrict__ Aimg) {
  const int tid = threadIdx.x;
  const int row = blockIdx.x * 8 + (tid >> 5);
  const int ch = tid & 31;           // kt = ch>>2, chunk c = ch&3
  const int kt = ch >> 2, c = ch & 3;
  const int rb = row >> 7, r = row & 127;
  const float4 z0 = *(const float4*)(Z + (size_t)row * D_DIM + kt * 32 + c * 8);
  const float4 z1 = *(const float4*)(Z + (size_t)row * D_DIM + kt * 32 + c * 8 + 4);
  u16x8 h, l;
  h[0] = f2bf(z0.x); l[0] = f2bf(z0.x - bf2f(h[0]));
  h[1] = f2bf(z0.y); l[1] = f2bf(z0.y - bf2f(h[1]));
  h[2] = f2bf(z0.z); l[2] = f2bf(z0.z - bf2f(h[2]));
  h[3] = f2bf(z0.w); l[3] = f2bf(z0.w - bf2f(h[3]));
  h[4] = f2bf(z1.x); l[4] = f2bf(z1.x - bf2f(h[4]));
  h[5] = f2bf(z1.y); l[5] = f2bf(z1.y - bf2f(h[5]));
  h[6] = f2bf(z1.z); l[6] = f2bf(z1.z - bf2f(h[6]));
  h[7] = f2bf(z1.w); l[7] = f2bf(z1.w - bf2f(h[7]));
  const int cs = c ^ ((r >> 1) & 3);
  const size_t off = (size_t)r * 64 + cs * 16;
  *(u16x8*)(Aimg + (size_t)(rb * 16 + kt) * 8192 + off) = h;
  *(u16x8*)(Aimg + (size_t)(rb * 16 + 8 + kt) * 8192 + off) = l;
}

// ---------------- prep: E -> packed swizzled image + e_sq ----------------
__global__ __launch_bounds__(256) void prep_e(const float* __restrict__ E,
                                              char* __restrict__ Bimg,
                                              float* __restrict__ esqg) {
  const int tid = threadIdx.x;
  const int code = blockIdx.x * 8 + (tid >> 5);
  const int ch = tid & 31;
  const int kt = ch >> 2, c = ch & 3;
  const int ntg = code >> 7, r = code & 127;
  const float4 e0 = *(const float4*)(E + (size_t)code * D_DIM + kt * 32 + c * 8);
  const float4 e1 = *(const float4*)(E + (size_t)code * D_DIM + kt * 32 + c * 8 + 4);
  u16x8 h, l;
  h[0] = f2bf(e0.x); l[0] = f2bf(e0.x - bf2f(h[0]));
  h[1] = f2bf(e0.y); l[1] = f2bf(e0.y - bf2f(h[1]));
  h[2] = f2bf(e0.z); l[2] = f2bf(e0.z - bf2f(h[2]));
  h[3] = f2bf(e0.w); l[3] = f2bf(e0.w - bf2f(h[3]));
  h[4] = f2bf(e1.x); l[4] = f2bf(e1.x - bf2f(h[4]));
  h[5] = f2bf(e1.y); l[5] = f2bf(e1.y - bf2f(h[5]));
  h[6] = f2bf(e1.z); l[6] = f2bf(e1.z - bf2f(h[6]));
  h[7] = f2bf(e1.w); l[7] = f2bf(e1.w - bf2f(h[7]));
  const int cs = c ^ ((r >> 1) & 3);
  const size_t off = (size_t)r * 64 + cs * 16;
  *(u16x8*)(Bimg + (size_t)(ntg * 16 + kt) * 8192 + off) = h;
  *(u16x8*)(Bimg + (size_t)(ntg * 16 + 8 + kt) * 8192 + off) = l;
  float s = e0.x * e0.x + e0.y * e0.y + e0.z * e0.z + e0.w * e0.w +
            e1.x * e1.x + e1.y * e1.y + e1.z * e1.z + e1.w * e1.w;
#pragma unroll
  for (int o = 16; o > 0; o >>= 1) s += __shfl_down(s, o, 32);
  if ((tid & 31) == 0) esqg[code] = s;
}

// ---------------- MFMA distance GEMM + fused top-2 argmin ----------------
// bid = rb*16 + ntp*8 + cb; block loops 4 code tiles (ntg = cb*8 + ntp*4 + nti).
// cb pins B slice to one XCD's L2; rb slowest -> co-resident blocks share A in L2.
// Per k-step: stage {Ahi,Alo,Bhi,Blo} once, 3 products (zh*eh + zh*el + zl*eh).
__global__ __launch_bounds__(256, 2) void argmin_mfma(
    const char* __restrict__ Aimg, const char* __restrict__ Bimg,
    const float* __restrict__ esqg, float4* __restrict__ partials) {
  __shared__ __align__(16) union {
    struct { char Ah[8192]; char Al[8192]; char Bh[8192]; char Bl[8192]; } t;  // 32 KB
    float4 mbuf[128][2];                                                       // 4 KB
  } u;
  __shared__ float esq_s[128];

  const int tid = threadIdx.x;
  const int lane = tid & 63;
  const int wid = tid >> 6;
  const int wrow = wid >> 1, wcol = wid & 1;
  const int lrow = lane & 15, lgrp = lane >> 4;
  const int cb = blockIdx.x & 7;
  const int ntp = (blockIdx.x >> 3) & 1;
  const int rb = blockIdx.x >> 4;

  float s1[16], s2[16]; int c1[16], c2[16];
#pragma unroll
  for (int i = 0; i < 16; i++) { s1[i] = 3.4e38f; s2[i] = 3.4e38f; c1[i] = 0; c2[i] = 0; }

  // frag read: row R's logical chunk lgrp lives at slot lgrp ^ ((R>>1)&3);
  // R = w*64 + rf*16 + lrow -> XOR term depends only on lrow.
  const int sw = (lrow >> 1) & 3;
  const int aoff = (wrow * 64 + lrow) * 64 + (lgrp ^ sw) * 16;
  const int boff = (wcol * 64 + lrow) * 64 + (lgrp ^ sw) * 16;
  const char* Abase = Aimg + (size_t)rb * (16u * 8192u);

  for (int nti = 0; nti < 4; nti++) {
    const int ntg = cb * 8 + ntp * 4 + nti;
    const char* Bbase = Bimg + (size_t)ntg * (16u * 8192u);

    f32x4 acc[4][4];
#pragma unroll
    for (int i = 0; i < 4; i++)
#pragma unroll
      for (int j = 0; j < 4; j++) acc[i][j] = (f32x4){0.f, 0.f, 0.f, 0.f};

    for (int k = 0; k < 8; k++) {
      __syncthreads();  // prior LDS reads (and prior epilogue's esq reads) done
      if (k == 0 && tid < 128) esq_s[tid] = esqg[ntg * 128 + tid];
      const char* ah = Abase + (size_t)k * 8192;
      const char* al = Abase + (size_t)(8 + k) * 8192;
      const char* bh = Bbase + (size_t)k * 8192;
      const char* bl = Bbase + (size_t)(8 + k) * 8192;
      gld16(ah + tid * 16, u.t.Ah + tid * 16);
      gld16(ah + 4096 + tid * 16, u.t.Ah + 4096 + tid * 16);
      gld16(al + tid * 16, u.t.Al + tid * 16);
      gld16(al + 4096 + tid * 16, u.t.Al + 4096 + tid * 16);
      gld16(bh + tid * 16, u.t.Bh + tid * 16);
      gld16(bh + 4096 + tid * 16, u.t.Bh + 4096 + tid * 16);
      gld16(bl + tid * 16, u.t.Bl + tid * 16);
      gld16(bl + 4096 + tid * 16, u.t.Bl + 4096 + tid * 16);
      __syncthreads();  // compiler drains vmcnt before barrier

      bf16x8 afh[4], afl[4], bfh[4], bfl[4];
#pragma unroll
      for (int rf = 0; rf < 4; rf++) {
        afh[rf] = *(const bf16x8*)(u.t.Ah + aoff + rf * 1024);
        afl[rf] = *(const bf16x8*)(u.t.Al + aoff + rf * 1024);
      }
#pragma unroll
      for (int cf = 0; cf < 4; cf++) {
        bfh[cf] = *(const bf16x8*)(u.t.Bh + boff + cf * 1024);
        bfl[cf] = *(const bf16x8*)(u.t.Bl + boff + cf * 1024);
      }
#pragma unroll
      for (int rf = 0; rf < 4; rf++)
#pragma unroll
        for (int cf = 0; cf < 4; cf++) {
          acc[rf][cf] = __builtin_amdgcn_mfma_f32_16x16x32_bf16(afh[rf], bfh[cf], acc[rf][cf], 0, 0, 0);
          acc[rf][cf] = __builtin_amdgcn_mfma_f32_16x16x32_bf16(afh[rf], bfl[cf], acc[rf][cf], 0, 0, 0);
          acc[rf][cf] = __builtin_amdgcn_mfma_f32_16x16x32_bf16(afl[rf], bfh[cf], acc[rf][cf], 0, 0, 0);
        }
    }

    // epilogue: dist = e_sq - 2*dot; exact top2-of-4 -> merge into running top2.
    // Later tiles have strictly higher codes, so keep-old-on-tie = lower index.
    float eq[4];
#pragma unroll
    for (int cf = 0; cf < 4; cf++) eq[cf] = esq_s[wcol * 64 + cf * 16 + lrow];
    const int code0 = ntg * 128 + wcol * 64 + lrow;
#pragma unroll
    for (int rf = 0; rf < 4; rf++)
#pragma unroll
      for (int reg = 0; reg < 4; reg++) {
        const int r = rf * 4 + reg;
        float v0 = fmaf(-2.f, acc[rf][0][reg], eq[0]);
        float v1 = fmaf(-2.f, acc[rf][1][reg], eq[1]);
        float v2 = fmaf(-2.f, acc[rf][2][reg], eq[2]);
        float v3 = fmaf(-2.f, acc[rf][3][reg], eq[3]);
        float a1 = v0, a2 = v1; int ka1 = code0, ka2 = code0 + 16;
        if (v1 < v0) { a1 = v1; ka1 = code0 + 16; a2 = v0; ka2 = code0; }
        float b1v = v2, b2v = v3; int kb1 = code0 + 32, kb2 = code0 + 48;
        if (v3 < v2) { b1v = v3; kb1 = code0 + 48; b2v = v2; kb2 = code0 + 32; }
        float m1, m2; int k1, k2;
        if (a1 <= b1v) {
          m1 = a1; k1 = ka1;
          if (b1v < a2) { m2 = b1v; k2 = kb1; } else { m2 = a2; k2 = ka2; }
        } else {
          m1 = b1v; k1 = kb1;
          if (a1 <= b2v) { m2 = a1; k2 = ka1; } else { m2 = b2v; k2 = kb2; }
        }
        // merge sorted pair (m1,m2) into sorted running (s1,s2)
        if (m1 < s1[r]) {
          s2[r] = (m2 < s1[r]) ? m2 : s1[r];
          c2[r] = (m2 < s1[r]) ? k2 : c1[r];
          s1[r] = m1; c1[r] = k1;
        } else if (m1 < s2[r]) {
          s2[r] = m1; c2[r] = k1;
        }
      }
  }

  // shuffle-butterfly merge across the 16 lrow lanes (disjoint code columns;
  // lexicographic (val, idx) compare keeps lowest-index-wins on ties)
#pragma unroll
  for (int r = 0; r < 16; r++) {
#pragma unroll
    for (int m = 1; m <= 8; m <<= 1) {
      float o1 = __shfl_xor(s1[r], m); int k1 = __shfl_xor(c1[r], m);
      float o2 = __shfl_xor(s2[r], m); int k2 = __shfl_xor(c2[r], m);
      bool t1 = (o1 < s1[r]) || (o1 == s1[r] && k1 < c1[r]);
      bool t2 = (o1 < s2[r]) || (o1 == s2[r] && k1 < c2[r]);
      float ns2 = t1 ? s1[r] : (t2 ? o1 : s2[r]);
      int   nc2 = t1 ? c1[r] : (t2 ? k1 : c2[r]);
      s1[r] = t1 ? o1 : s1[r]; c1[r] = t1 ? k1 : c1[r];
      s2[r] = ns2; c2[r] = nc2;
      bool u1 = (o2 < s1[r]) || (o2 == s1[r] && k2 < c1[r]);
      bool u2 = (o2 < s2[r]) || (o2 == s2[r] && k2 < c2[r]);
      ns2 = u1 ? s1[r] : (u2 ? o2 : s2[r]);
      nc2 = u1 ? c1[r] : (u2 ? k2 : c2[r]);
      s1[r] = u1 ? o2 : s1[r]; c1[r] = u1 ? k2 : c1[r];
      s2[r] = ns2; c2[r] = nc2;
    }
  }

  __syncthreads();  // all tile reads done; reuse union as merge buffer
  if (lrow == 0) {
#pragma unroll
    for (int rf = 0; rf < 4; rf++)
#pragma unroll
      for (int reg = 0; reg < 4; reg++) {
        const int r = rf * 4 + reg;
        const int row = wrow * 64 + rf * 16 + lgrp * 4 + reg;
        float4 p;
        p.x = s1[r]; p.y = __int_as_float(c1[r]);
        p.z = s2[r]; p.w = __int_as_float(c2[r]);
        u.mbuf[row][wcol] = p;
      }
  }
  __syncthreads();
  if (tid < 128) {
    float4 pa = u.mbuf[tid][0];
    float4 pb = u.mbuf[tid][1];
    float D1 = pa.x; int C1 = __float_as_int(pa.y);
    float D2 = pa.z; int C2 = __float_as_int(pa.w);
    float a = pb.x; int ka = __float_as_int(pb.y);
    float b = pb.z; int kb = __float_as_int(pb.w);
    if (a < D1 || (a == D1 && ka < C1)) { D2 = D1; C2 = C1; D1 = a; C1 = ka; }
    else if (a < D2 || (a == D2 && ka < C2)) { D2 = a; C2 = ka; }
    if (b < D1 || (b == D1 && kb < C1)) { D2 = D1; C2 = C1; D1 = b; C1 = kb; }
    else if (b < D2 || (b == D2 && kb < C2)) { D2 = b; C2 = kb; }
    float4 p;
    p.x = D1; p.y = __int_as_float(C1); p.z = D2; p.w = __int_as_float(C2);
    partials[(size_t)(ntp * 8 + cb) * N_TOT + rb * 128 + tid] = p;
  }
}

// ---------------- merge 16 slice partials + fp64 rescore ----------------
__global__ __launch_bounds__(128) void merge_rescore(
    const float* __restrict__ Z, const float* __restrict__ E,
    const float4* __restrict__ partials, float* __restrict__ out_idx_f) {
  const int row = blockIdx.x * 128 + threadIdx.x;
  float D1 = 3.4e38f, D2 = 3.4e38f; int C1 = 0, C2 = 0;
  for (int s = 0; s < 16; s++) {
    float4 p = partials[(size_t)s * N_TOT + row];
    float a = p.x; int ka = __float_as_int(p.y);
    float b = p.z; int kb = __float_as_int(p.w);
    if (a < D1 || (a == D1 && ka < C1)) { D2 = D1; C2 = C1; D1 = a; C1 = ka; }
    else if (a < D2 || (a == D2 && ka < C2)) { D2 = a; C2 = ka; }
    if (b < D1 || (b == D1 && kb < C1)) { D2 = D1; C2 = C1; D1 = b; C1 = kb; }
    else if (b < D2 || (b == D2 && kb < C2)) { D2 = b; C2 = kb; }
  }
  // fp64 rescore of top-2: resolves near-ties against the true distance
  const float* zp = Z + (size_t)row * D_DIM;
  const float* ep1 = E + (size_t)C1 * D_DIM;
  const float* ep2 = E + (size_t)C2 * D_DIM;
  double dd1 = 0.0, dd2 = 0.0;
  for (int d = 0; d < D_DIM; d += 4) {
    const float4 zv = *(const float4*)(zp + d);
    const float4 e1v = *(const float4*)(ep1 + d);
    const float4 e2v = *(const float4*)(ep2 + d);
    double t;
    t = (double)zv.x - (double)e1v.x; dd1 += t * t;
    t = (double)zv.y - (double)e1v.y; dd1 += t * t;
    t = (double)zv.z - (double)e1v.z; dd1 += t * t;
    t = (double)zv.w - (double)e1v.w; dd1 += t * t;
    t = (double)zv.x - (double)e2v.x; dd2 += t * t;
    t = (double)zv.y - (double)e2v.y; dd2 += t * t;
    t = (double)zv.z - (double)e2v.z; dd2 += t * t;
    t = (double)zv.w - (double)e2v.w; dd2 += t * t;
  }
  int fin = C1;
  if (dd2 < dd1 || (dd2 == dd1 && C2 < C1)) fin = C2;
  out_idx_f[row] = (float)fin;
}

// ---------------- gather z_q, loss partial per block (no hot atomic) ----------------
__global__ __launch_bounds__(256) void gather_kernel(
    const float* __restrict__ Z, const float* __restrict__ E,
    const float* __restrict__ idx_f, float* __restrict__ zq_out,
    float* __restrict__ counts, float* __restrict__ loss_part) {
  const int t = threadIdx.x;
  float lsum = 0.0f;
  for (int rr = 0; rr < 16; rr++) {
    const int row = blockIdx.x * 16 + rr;
    const int c = (int)idx_f[row];
    const float e = E[(size_t)c * D_DIM + t];
    const float z = Z[(size_t)row * D_DIM + t];
    zq_out[(size_t)row * D_DIM + t] = e;
    const float d = z - e;
    lsum += d * d;
    if (t == 0) atomicAdd(&counts[c], 1.0f);  // 8192 addresses, low contention
  }
#pragma unroll
  for (int off = 32; off > 0; off >>= 1) lsum += __shfl_down(lsum, off);
  __shared__ float wsum[4];
  if ((t & 63) == 0) wsum[t >> 6] = lsum;
  __syncthreads();
  if (t == 0) loss_part[blockIdx.x] = wsum[0] + wsum[1] + wsum[2] + wsum[3];
}

// ---------------- loss scale + perplexity ----------------
__global__ __launch_bounds__(256) void final_kernel(
    const float* __restrict__ counts, const float* __restrict__ loss_part,
    float* __restrict__ out) {
  const int t = threadIdx.x;
  float h = 0.0f, ls = 0.0f;
  for (int k = t; k < K_CB; k += 256) {
    const float p = counts[k] * (1.0f / (float)N_TOT);
    h += p * logf(p + 1e-12f);
  }
  for (int k = t; k < 2048; k += 256) ls += loss_part[k];
#pragma unroll
  for (int off = 32; off > 0; off >>= 1) {
    h += __shfl_down(h, off);
    ls += __shfl_down(ls, off);
  }
  __shared__ float ws4[4], ls4[4];
  if ((t & 63) == 0) { ws4[t >> 6] = h; ls4[t >> 6] = ls; }
  __syncthreads();
  if (t == 0) {
    const float H = ws4[0] + ws4[1] + ws4[2] + ws4[3];
    const float L = ls4[0] + ls4[1] + ls4[2] + ls4[3];
    out[OUT_LOSS] = 1.25f * L * (1.0f / (float)(N_TOT * D_DIM));
    out[OUT_PERP] = expf(-H);
  }
}

extern "C" void kernel_launch(void* const* d_in, const int* in_sizes, int n_in,
                              void* d_out, int out_size, void* d_ws, size_t ws_size,
                              hipStream_t stream) {
  (void)in_sizes; (void)n_in; (void)out_size; (void)ws_size;
  const float* Z = (const float*)d_in[0];
  const float* E = (const float*)d_in[1];
  float* out = (float*)d_out;
  char* ws = (char*)d_ws;
  char* Aimg = ws + WS_AIMG;
  char* Bimg = ws + WS_BIMG;
  float4* partials = (float4*)(ws + WS_PART);
  float* esqg = (float*)(ws + WS_ESQ);
  float* counts = (float*)(ws + WS_COUNTS);
  float* loss_part = (float*)(ws + WS_LPART);

  hipMemsetAsync(ws + WS_COUNTS, 0, 32768, stream);  // counts only
  prep_z<<<dim3(4096), dim3(256), 0, stream>>>(Z, Aimg);
  prep_e<<<dim3(1024), dim3(256), 0, stream>>>(E, Bimg, esqg);
  argmin_mfma<<<dim3(4096), dim3(256), 0, stream>>>(Aimg, Bimg, esqg, partials);
  merge_rescore<<<dim3(256), dim3(128), 0, stream>>>(Z, E, partials, out + OUT_IDX);
  gather_kernel<<<dim3(2048), dim3(256), 0, stream>>>(Z, E, out + OUT_IDX, out, counts, loss_part);
  final_kernel<<<dim3(1), dim3(256), 0, stream>>>(counts, loss_part, out);
}

// Round 5
// 666.759 us; speedup vs baseline: 4.3518x; 1.2927x over previous
//
#include <hip/hip_runtime.h>
#include <math.h>

#define N_TOT 32768
#define K_CB 8192
#define D_DIM 256

#define OUT_IDX  (N_TOT * D_DIM)   // 8388608
#define OUT_LOSS (OUT_IDX + N_TOT) // 8421376
#define OUT_PERP (OUT_LOSS + 1)

// ---- workspace layout (bytes), total 50,405,376 (proven budget) ----
#define WS_AIMG   0u
#define AIMG_SZ   (256u * 16u * 8192u)           // 33,554,432
#define WS_BIMG   (WS_AIMG + AIMG_SZ)
#define BIMG_SZ   (64u * 16u * 8192u)            // 8,388,608
#define WS_PART   (WS_BIMG + BIMG_SZ)            // 16 slices x 32768 x float4
#define PART_SZ   (16u * 32768u * 16u)           // 8,388,608
#define WS_ESQ    (WS_PART + PART_SZ)            // 8192 f32
#define WS_COUNTS (WS_ESQ + 32768u)              // 8192 f32
#define WS_LPART  (WS_COUNTS + 32768u)           // 2048 f32 loss partials

typedef short bf16x8 __attribute__((ext_vector_type(8)));
typedef float f32x4  __attribute__((ext_vector_type(4)));
typedef unsigned short u16x8 __attribute__((ext_vector_type(8)));

__device__ __forceinline__ unsigned short f2bf(float x) {  // RNE f32 -> bf16
  unsigned int b = __float_as_uint(x);
  b = b + 0x7FFFu + ((b >> 16) & 1u);
  return (unsigned short)(b >> 16);
}
__device__ __forceinline__ float bf2f(unsigned short h) {
  return __uint_as_float(((unsigned int)h) << 16);
}
__device__ __forceinline__ void gld16(const void* g, void* l) {
  __builtin_amdgcn_global_load_lds(
      (const __attribute__((address_space(1))) void*)g,
      (__attribute__((address_space(3))) void*)l, 16, 0, 0);
}

// ---------------- prep: Z -> packed swizzled bf16 hi/lo tile image ----------------
// Chunk c of row r stored at slot c ^ ((r>>1)&3): linear global_load_lds lands it
// pre-swizzled; the frag ds_read applies the same XOR (both-sides rule).
__global__ __launch_bounds__(256) void prep_z(const float* __restrict__ Z,
                                              char* __restrict__ Aimg) {
  const int tid = threadIdx.x;
  const int row = blockIdx.x * 8 + (tid >> 5);
  const int ch = tid & 31;           // kt = ch>>2, chunk c = ch&3
  const int kt = ch >> 2, c = ch & 3;
  const int rb = row >> 7, r = row & 127;
  const float4 z0 = *(const float4*)(Z + (size_t)row * D_DIM + kt * 32 + c * 8);
  const float4 z1 = *(const float4*)(Z + (size_t)row * D_DIM + kt * 32 + c * 8 + 4);
  u16x8 h, l;
  h[0] = f2bf(z0.x); l[0] = f2bf(z0.x - bf2f(h[0]));
  h[1] = f2bf(z0.y); l[1] = f2bf(z0.y - bf2f(h[1]));
  h[2] = f2bf(z0.z); l[2] = f2bf(z0.z - bf2f(h[2]));
  h[3] = f2bf(z0.w); l[3] = f2bf(z0.w - bf2f(h[3]));
  h[4] = f2bf(z1.x); l[4] = f2bf(z1.x - bf2f(h[4]));
  h[5] = f2bf(z1.y); l[5] = f2bf(z1.y - bf2f(h[5]));
  h[6] = f2bf(z1.z); l[6] = f2bf(z1.z - bf2f(h[6]));
  h[7] = f2bf(z1.w); l[7] = f2bf(z1.w - bf2f(h[7]));
  const int cs = c ^ ((r >> 1) & 3);
  const size_t off = (size_t)r * 64 + cs * 16;
  *(u16x8*)(Aimg + (size_t)(rb * 16 + kt) * 8192 + off) = h;
  *(u16x8*)(Aimg + (size_t)(rb * 16 + 8 + kt) * 8192 + off) = l;
}

// ---------------- prep: E -> packed swizzled image + e_sq ----------------
__global__ __launch_bounds__(256) void prep_e(const float* __restrict__ E,
                                              char* __restrict__ Bimg,
                                              float* __restrict__ esqg) {
  const int tid = threadIdx.x;
  const int code = blockIdx.x * 8 + (tid >> 5);
  const int ch = tid & 31;
  const int kt = ch >> 2, c = ch & 3;
  const int ntg = code >> 7, r = code & 127;
  const float4 e0 = *(const float4*)(E + (size_t)code * D_DIM + kt * 32 + c * 8);
  const float4 e1 = *(const float4*)(E + (size_t)code * D_DIM + kt * 32 + c * 8 + 4);
  u16x8 h, l;
  h[0] = f2bf(e0.x); l[0] = f2bf(e0.x - bf2f(h[0]));
  h[1] = f2bf(e0.y); l[1] = f2bf(e0.y - bf2f(h[1]));
  h[2] = f2bf(e0.z); l[2] = f2bf(e0.z - bf2f(h[2]));
  h[3] = f2bf(e0.w); l[3] = f2bf(e0.w - bf2f(h[3]));
  h[4] = f2bf(e1.x); l[4] = f2bf(e1.x - bf2f(h[4]));
  h[5] = f2bf(e1.y); l[5] = f2bf(e1.y - bf2f(h[5]));
  h[6] = f2bf(e1.z); l[6] = f2bf(e1.z - bf2f(h[6]));
  h[7] = f2bf(e1.w); l[7] = f2bf(e1.w - bf2f(h[7]));
  const int cs = c ^ ((r >> 1) & 3);
  const size_t off = (size_t)r * 64 + cs * 16;
  *(u16x8*)(Bimg + (size_t)(ntg * 16 + kt) * 8192 + off) = h;
  *(u16x8*)(Bimg + (size_t)(ntg * 16 + 8 + kt) * 8192 + off) = l;
  float s = e0.x * e0.x + e0.y * e0.y + e0.z * e0.z + e0.w * e0.w +
            e1.x * e1.x + e1.y * e1.y + e1.z * e1.z + e1.w * e1.w;
#pragma unroll
  for (int o = 16; o > 0; o >>= 1) s += __shfl_down(s, o, 32);
  if ((tid & 31) == 0) esqg[code] = s;
}

// ---------------- MFMA distance GEMM + fused top-2 argmin ----------------
// bid = rb*16 + ntp*8 + cb; block loops 4 code tiles (ntg = cb*8 + ntp*4 + nti).
// Double-buffered LDS, depth-1 prefetch: stage k-step kk+1 into buf[1-bi] BEFORE
// computing kk from buf[bi]; single barrier per k-step (vmcnt drain lands after
// the MFMA work). Loop unrolled x2 so buffer index is compile-time.
__global__ __launch_bounds__(256, 2) void argmin_mfma(
    const char* __restrict__ Aimg, const char* __restrict__ Bimg,
    const float* __restrict__ esqg, float4* __restrict__ partials) {
  __shared__ __align__(16) union {
    struct { char Ah[8192]; char Al[8192]; char Bh[8192]; char Bl[8192]; } t[2];  // 64 KB
    float4 mbuf[128][2];                                                          // 4 KB
  } u;
  __shared__ float esq_s[512];  // all 4 tiles' e_sq

  const int tid = threadIdx.x;
  const int lane = tid & 63;
  const int wid = tid >> 6;
  const int wrow = wid >> 1, wcol = wid & 1;
  const int lrow = lane & 15, lgrp = lane >> 4;
  const int cb = blockIdx.x & 7;
  const int ntp = (blockIdx.x >> 3) & 1;
  const int rb = blockIdx.x >> 4;
  const int ntg0 = cb * 8 + ntp * 4;

  // frag read: row R's logical chunk lgrp lives at slot lgrp ^ ((R>>1)&3);
  // R = w*64 + rf*16 + lrow -> XOR term depends only on lrow.
  const int sw = (lrow >> 1) & 3;
  const int aoff = (wrow * 64 + lrow) * 64 + (lgrp ^ sw) * 16;
  const int boff = (wcol * 64 + lrow) * 64 + (lgrp ^ sw) * 16;
  const char* Abase = Aimg + (size_t)rb * (16u * 8192u);
  const char* Bbase0 = Bimg + (size_t)ntg0 * (16u * 8192u);
  const int soff = tid * 16;

  float s1[16], s2[16]; int c1[16], c2[16];
#pragma unroll
  for (int i = 0; i < 16; i++) { s1[i] = 3.4e38f; s2[i] = 3.4e38f; c1[i] = 0; c2[i] = 0; }

#define STAGE_K(kk, BI) do {                                                   \
    const int k_ = (kk) & 7, nti_ = (kk) >> 3;                                 \
    const char* ah_ = Abase + (size_t)k_ * 8192;                               \
    const char* al_ = Abase + (size_t)(8 + k_) * 8192;                         \
    const char* bb_ = Bbase0 + (size_t)nti_ * (16u * 8192u);                   \
    const char* bh_ = bb_ + (size_t)k_ * 8192;                                 \
    const char* bl_ = bb_ + (size_t)(8 + k_) * 8192;                           \
    gld16(ah_ + soff,        u.t[BI].Ah + soff);                               \
    gld16(ah_ + 4096 + soff, u.t[BI].Ah + 4096 + soff);                        \
    gld16(al_ + soff,        u.t[BI].Al + soff);                               \
    gld16(al_ + 4096 + soff, u.t[BI].Al + 4096 + soff);                        \
    gld16(bh_ + soff,        u.t[BI].Bh + soff);                               \
    gld16(bh_ + 4096 + soff, u.t[BI].Bh + 4096 + soff);                        \
    gld16(bl_ + soff,        u.t[BI].Bl + soff);                               \
    gld16(bl_ + 4096 + soff, u.t[BI].Bl + 4096 + soff);                        \
  } while (0)

#define COMPUTE_K(BI) do {                                                     \
    bf16x8 afh[4], afl[4], bfh[4], bfl[4];                                     \
    _Pragma("unroll")                                                          \
    for (int rf = 0; rf < 4; rf++) {                                           \
      afh[rf] = *(const bf16x8*)(u.t[BI].Ah + aoff + rf * 1024);               \
      afl[rf] = *(const bf16x8*)(u.t[BI].Al + aoff + rf * 1024);               \
    }                                                                          \
    _Pragma("unroll")                                                          \
    for (int cf = 0; cf < 4; cf++) {                                           \
      bfh[cf] = *(const bf16x8*)(u.t[BI].Bh + boff + cf * 1024);               \
      bfl[cf] = *(const bf16x8*)(u.t[BI].Bl + boff + cf * 1024);               \
    }                                                                          \
    _Pragma("unroll")                                                          \
    for (int rf = 0; rf < 4; rf++)                                             \
      _Pragma("unroll")                                                        \
      for (int cf = 0; cf < 4; cf++) {                                         \
        acc[rf][cf] = __builtin_amdgcn_mfma_f32_16x16x32_bf16(afh[rf], bfh[cf], acc[rf][cf], 0, 0, 0); \
        acc[rf][cf] = __builtin_amdgcn_mfma_f32_16x16x32_bf16(afh[rf], bfl[cf], acc[rf][cf], 0, 0, 0); \
        acc[rf][cf] = __builtin_amdgcn_mfma_f32_16x16x32_bf16(afl[rf], bfh[cf], acc[rf][cf], 0, 0, 0); \
      }                                                                        \
  } while (0)

  // prologue: esq for all 4 tiles + k-step 0 into buf0
  esq_s[tid] = esqg[ntg0 * 128 + tid];
  esq_s[tid + 256] = esqg[ntg0 * 128 + tid + 256];
  STAGE_K(0, 0);

  f32x4 acc[4][4];
#pragma unroll
  for (int i = 0; i < 4; i++)
#pragma unroll
    for (int j = 0; j < 4; j++) acc[i][j] = (f32x4){0.f, 0.f, 0.f, 0.f};

  __syncthreads();  // buf0 + esq_s ready

  for (int kp = 0; kp < 16; kp++) {
    const int kk0 = kp * 2;
    // ---- phase A: compute buf0, prefetch kk0+1 -> buf1 ----
    STAGE_K(kk0 + 1, 1);
    COMPUTE_K(0);
    __syncthreads();  // buf1 landed; all waves done reading buf0
    // ---- phase B: compute buf1, prefetch kk0+2 -> buf0 ----
    if (kp < 15) STAGE_K(kk0 + 2, 0);
    COMPUTE_K(1);
    if ((kp & 3) == 3) {
      // epilogue for nti = kp>>2: dist = e_sq - 2*dot; exact top2-of-4 ->
      // merge into running top2 (later tiles = higher codes; ties keep old).
      const int nti = kp >> 2;
      const int ntg = ntg0 + nti;
      const int code0 = ntg * 128 + wcol * 64 + lrow;
      float eq[4];
#pragma unroll
      for (int cf = 0; cf < 4; cf++) eq[cf] = esq_s[nti * 128 + wcol * 64 + cf * 16 + lrow];
#pragma unroll
      for (int rf = 0; rf < 4; rf++)
#pragma unroll
        for (int reg = 0; reg < 4; reg++) {
          const int r = rf * 4 + reg;
          float v0 = fmaf(-2.f, acc[rf][0][reg], eq[0]);
          float v1 = fmaf(-2.f, acc[rf][1][reg], eq[1]);
          float v2 = fmaf(-2.f, acc[rf][2][reg], eq[2]);
          float v3 = fmaf(-2.f, acc[rf][3][reg], eq[3]);
          float a1 = v0, a2 = v1; int ka1 = code0, ka2 = code0 + 16;
          if (v1 < v0) { a1 = v1; ka1 = code0 + 16; a2 = v0; ka2 = code0; }
          float b1v = v2, b2v = v3; int kb1 = code0 + 32, kb2 = code0 + 48;
          if (v3 < v2) { b1v = v3; kb1 = code0 + 48; b2v = v2; kb2 = code0 + 32; }
          float m1, m2; int k1, k2;
          if (a1 <= b1v) {
            m1 = a1; k1 = ka1;
            if (b1v < a2) { m2 = b1v; k2 = kb1; } else { m2 = a2; k2 = ka2; }
          } else {
            m1 = b1v; k1 = kb1;
            if (a1 <= b2v) { m2 = a1; k2 = ka1; } else { m2 = b2v; k2 = kb2; }
          }
          if (m1 < s1[r]) {
            s2[r] = (m2 < s1[r]) ? m2 : s1[r];
            c2[r] = (m2 < s1[r]) ? k2 : c1[r];
            s1[r] = m1; c1[r] = k1;
          } else if (m1 < s2[r]) {
            s2[r] = m1; c2[r] = k1;
          }
        }
#pragma unroll
      for (int i = 0; i < 4; i++)
#pragma unroll
        for (int j = 0; j < 4; j++) acc[i][j] = (f32x4){0.f, 0.f, 0.f, 0.f};
    }
    __syncthreads();  // buf0 landed; all waves done reading buf1
  }
#undef STAGE_K
#undef COMPUTE_K

  // shuffle-butterfly merge across the 16 lrow lanes (disjoint code columns;
  // lexicographic (val, idx) compare keeps lowest-index-wins on ties)
#pragma unroll
  for (int r = 0; r < 16; r++) {
#pragma unroll
    for (int m = 1; m <= 8; m <<= 1) {
      float o1 = __shfl_xor(s1[r], m); int k1 = __shfl_xor(c1[r], m);
      float o2 = __shfl_xor(s2[r], m); int k2 = __shfl_xor(c2[r], m);
      bool t1 = (o1 < s1[r]) || (o1 == s1[r] && k1 < c1[r]);
      bool t2 = (o1 < s2[r]) || (o1 == s2[r] && k1 < c2[r]);
      float ns2 = t1 ? s1[r] : (t2 ? o1 : s2[r]);
      int   nc2 = t1 ? c1[r] : (t2 ? k1 : c2[r]);
      s1[r] = t1 ? o1 : s1[r]; c1[r] = t1 ? k1 : c1[r];
      s2[r] = ns2; c2[r] = nc2;
      bool u1 = (o2 < s1[r]) || (o2 == s1[r] && k2 < c1[r]);
      bool u2 = (o2 < s2[r]) || (o2 == s2[r] && k2 < c2[r]);
      ns2 = u1 ? s1[r] : (u2 ? o2 : s2[r]);
      nc2 = u1 ? c1[r] : (u2 ? k2 : c2[r]);
      s1[r] = u1 ? o2 : s1[r]; c1[r] = u1 ? k2 : c1[r];
      s2[r] = ns2; c2[r] = nc2;
    }
  }

  __syncthreads();  // all tile reads done (last loop barrier also covers this)
  if (lrow == 0) {
#pragma unroll
    for (int rf = 0; rf < 4; rf++)
#pragma unroll
      for (int reg = 0; reg < 4; reg++) {
        const int r = rf * 4 + reg;
        const int row = wrow * 64 + rf * 16 + lgrp * 4 + reg;
        float4 p;
        p.x = s1[r]; p.y = __int_as_float(c1[r]);
        p.z = s2[r]; p.w = __int_as_float(c2[r]);
        u.mbuf[row][wcol] = p;
      }
  }
  __syncthreads();
  if (tid < 128) {
    float4 pa = u.mbuf[tid][0];
    float4 pb = u.mbuf[tid][1];
    float D1 = pa.x; int C1 = __float_as_int(pa.y);
    float D2 = pa.z; int C2 = __float_as_int(pa.w);
    float a = pb.x; int ka = __float_as_int(pb.y);
    float b = pb.z; int kb = __float_as_int(pb.w);
    if (a < D1 || (a == D1 && ka < C1)) { D2 = D1; C2 = C1; D1 = a; C1 = ka; }
    else if (a < D2 || (a == D2 && ka < C2)) { D2 = a; C2 = ka; }
    if (b < D1 || (b == D1 && kb < C1)) { D2 = D1; C2 = C1; D1 = b; C1 = kb; }
    else if (b < D2 || (b == D2 && kb < C2)) { D2 = b; C2 = kb; }
    float4 p;
    p.x = D1; p.y = __int_as_float(C1); p.z = D2; p.w = __int_as_float(C2);
    partials[(size_t)(ntp * 8 + cb) * N_TOT + rb * 128 + tid] = p;
  }
}

// ---------------- merge 16 slice partials + fp64 rescore ----------------
__global__ __launch_bounds__(128) void merge_rescore(
    const float* __restrict__ Z, const float* __restrict__ E,
    const float4* __restrict__ partials, float* __restrict__ out_idx_f) {
  const int row = blockIdx.x * 128 + threadIdx.x;
  float D1 = 3.4e38f, D2 = 3.4e38f; int C1 = 0, C2 = 0;
  for (int s = 0; s < 16; s++) {
    float4 p = partials[(size_t)s * N_TOT + row];
    float a = p.x; int ka = __float_as_int(p.y);
    float b = p.z; int kb = __float_as_int(p.w);
    if (a < D1 || (a == D1 && ka < C1)) { D2 = D1; C2 = C1; D1 = a; C1 = ka; }
    else if (a < D2 || (a == D2 && ka < C2)) { D2 = a; C2 = ka; }
    if (b < D1 || (b == D1 && kb < C1)) { D2 = D1; C2 = C1; D1 = b; C1 = kb; }
    else if (b < D2 || (b == D2 && kb < C2)) { D2 = b; C2 = kb; }
  }
  // fp64 rescore of top-2: resolves near-ties against the true distance
  const float* zp = Z + (size_t)row * D_DIM;
  const float* ep1 = E + (size_t)C1 * D_DIM;
  const float* ep2 = E + (size_t)C2 * D_DIM;
  double dd1 = 0.0, dd2 = 0.0;
  for (int d = 0; d < D_DIM; d += 4) {
    const float4 zv = *(const float4*)(zp + d);
    const float4 e1v = *(const float4*)(ep1 + d);
    const float4 e2v = *(const float4*)(ep2 + d);
    double t;
    t = (double)zv.x - (double)e1v.x; dd1 += t * t;
    t = (double)zv.y - (double)e1v.y; dd1 += t * t;
    t = (double)zv.z - (double)e1v.z; dd1 += t * t;
    t = (double)zv.w - (double)e1v.w; dd1 += t * t;
    t = (double)zv.x - (double)e2v.x; dd2 += t * t;
    t = (double)zv.y - (double)e2v.y; dd2 += t * t;
    t = (double)zv.z - (double)e2v.z; dd2 += t * t;
    t = (double)zv.w - (double)e2v.w; dd2 += t * t;
  }
  int fin = C1;
  if (dd2 < dd1 || (dd2 == dd1 && C2 < C1)) fin = C2;
  out_idx_f[row] = (float)fin;
}

// ---------------- gather z_q, loss partial per block (no hot atomic) ----------------
__global__ __launch_bounds__(256) void gather_kernel(
    const float* __restrict__ Z, const float* __restrict__ E,
    const float* __restrict__ idx_f, float* __restrict__ zq_out,
    float* __restrict__ counts, float* __restrict__ loss_part) {
  const int t = threadIdx.x;
  float lsum = 0.0f;
  for (int rr = 0; rr < 16; rr++) {
    const int row = blockIdx.x * 16 + rr;
    const int c = (int)idx_f[row];
    const float e = E[(size_t)c * D_DIM + t];
    const float z = Z[(size_t)row * D_DIM + t];
    zq_out[(size_t)row * D_DIM + t] = e;
    const float d = z - e;
    lsum += d * d;
    if (t == 0) atomicAdd(&counts[c], 1.0f);  // 8192 addresses, low contention
  }
#pragma unroll
  for (int off = 32; off > 0; off >>= 1) lsum += __shfl_down(lsum, off);
  __shared__ float wsum[4];
  if ((t & 63) == 0) wsum[t >> 6] = lsum;
  __syncthreads();
  if (t == 0) loss_part[blockIdx.x] = wsum[0] + wsum[1] + wsum[2] + wsum[3];
}

// ---------------- loss scale + perplexity ----------------
__global__ __launch_bounds__(256) void final_kernel(
    const float* __restrict__ counts, const float* __restrict__ loss_part,
    float* __restrict__ out) {
  const int t = threadIdx.x;
  float h = 0.0f, ls = 0.0f;
  for (int k = t; k < K_CB; k += 256) {
    const float p = counts[k] * (1.0f / (float)N_TOT);
    h += p * logf(p + 1e-12f);
  }
  for (int k = t; k < 2048; k += 256) ls += loss_part[k];
#pragma unroll
  for (int off = 32; off > 0; off >>= 1) {
    h += __shfl_down(h, off);
    ls += __shfl_down(ls, off);
  }
  __shared__ float ws4[4], ls4[4];
  if ((t & 63) == 0) { ws4[t >> 6] = h; ls4[t >> 6] = ls; }
  __syncthreads();
  if (t == 0) {
    const float H = ws4[0] + ws4[1] + ws4[2] + ws4[3];
    const float L = ls4[0] + ls4[1] + ls4[2] + ls4[3];
    out[OUT_LOSS] = 1.25f * L * (1.0f / (float)(N_TOT * D_DIM));
    out[OUT_PERP] = expf(-H);
  }
}

extern "C" void kernel_launch(void* const* d_in, const int* in_sizes, int n_in,
                              void* d_out, int out_size, void* d_ws, size_t ws_size,
                              hipStream_t stream) {
  (void)in_sizes; (void)n_in; (void)out_size; (void)ws_size;
  const float* Z = (const float*)d_in[0];
  const float* E = (const float*)d_in[1];
  float* out = (float*)d_out;
  char* ws = (char*)d_ws;
  char* Aimg = ws + WS_AIMG;
  char* Bimg = ws + WS_BIMG;
  float4* partials = (float4*)(ws + WS_PART);
  float* esqg = (float*)(ws + WS_ESQ);
  float* counts = (float*)(ws + WS_COUNTS);
  float* loss_part = (float*)(ws + WS_LPART);

  hipMemsetAsync(ws + WS_COUNTS, 0, 32768, stream);  // counts only
  prep_z<<<dim3(4096), dim3(256), 0, stream>>>(Z, Aimg);
  prep_e<<<dim3(1024), dim3(256), 0, stream>>>(E, Bimg, esqg);
  argmin_mfma<<<dim3(4096), dim3(256), 0, stream>>>(Aimg, Bimg, esqg, partials);
  merge_rescore<<<dim3(256), dim3(128), 0, stream>>>(Z, E, partials, out + OUT_IDX);
  gather_kernel<<<dim3(2048), dim3(256), 0, stream>>>(Z, E, out + OUT_IDX, out, counts, loss_part);
  final_kernel<<<dim3(1), dim3(256), 0, stream>>>(counts, loss_part, out);
}